// Round 1
// baseline (3354.403 us; speedup 1.0000x reference)
//
#include <hip/hip_runtime.h>
#include <hip/hip_bf16.h>

#define D 128

// ---------- edge-index dtype detection (int64 vs int32, on-device) ----------
__device__ __forceinline__ bool ei_is64(const int* ei32) {
    // For int64 data with values in [0, 2^31), every high word is 0.
    // For int32 data these are random src values; all-4-zero prob ~ 1e-20.
    return (ei32[1] | ei32[3] | ei32[5] | ei32[7]) == 0;
}

__device__ __forceinline__ int get_idx(const void* ei, bool is64, long long pos) {
    return is64 ? (int)((const long long*)ei)[pos] : ((const int*)ei)[pos];
}

// ---------- degree count ----------
__global__ __launch_bounds__(256) void deg_count_kernel(const void* __restrict__ ei,
                                                        int E, int* __restrict__ deg) {
    bool is64 = ei_is64((const int*)ei);
    int i = blockIdx.x * blockDim.x + threadIdx.x;
    if (i < E) {
        int d = get_idx(ei, is64, (long long)E + i);
        atomicAdd(&deg[d], 1);
    }
}

__global__ __launch_bounds__(256) void inv_deg_kernel(const int* __restrict__ deg,
                                                      float* __restrict__ inv, int N) {
    int i = blockIdx.x * blockDim.x + threadIdx.x;
    if (i < N) inv[i] = 1.0f / (float)max(deg[i], 1);
}

// ---------- scatter-add: one wave per edge, lane handles 2 floats ----------
__global__ __launch_bounds__(256) void scatter_add_kernel(const float* __restrict__ x,
                                                          const void* __restrict__ ei,
                                                          int E, float* __restrict__ agg) {
    bool is64 = ei_is64((const int*)ei);
    int lane = threadIdx.x & 63;
    int wave = blockIdx.x * (blockDim.x >> 6) + (threadIdx.x >> 6);
    int nw = gridDim.x * (blockDim.x >> 6);
    for (int e = wave; e < E; e += nw) {
        int s = get_idx(ei, is64, e);
        int d = get_idx(ei, is64, (long long)E + e);
        const float2 v = *reinterpret_cast<const float2*>(x + (size_t)s * D + lane * 2);
        float* p = agg + (size_t)d * D + lane * 2;
        atomicAdd(p, v.x);
        atomicAdd(p + 1, v.y);
    }
}

// ---------- fused SAGE GEMM: out[r][c] = b[c] + sum_k A[r][k]*W[k][c]
//   A = concat(agg[r]*inv[r], selfx[r])  (K=256), W = concat(Wl^T, Wr^T)
//   sW: bf16, XOR-swizzled so transpose-write and column-read are conflict-free
//   sA: [k][r] layout so the inner loop reads rows as float4 broadcasts
//   In-place safe when out == agg (reads staged before writes, per-block rows).
__global__ __launch_bounds__(256) void sage_gemm_kernel(
    const float* __restrict__ agg, const float* __restrict__ invd,
    const float* __restrict__ selfx, const float* __restrict__ Wl,
    const float* __restrict__ Wr, const float* __restrict__ bias,
    float* __restrict__ out, int N) {
    __shared__ __hip_bfloat16 sW[256][128];  // 64 KB
    __shared__ float sA[256][16];            // 16 KB
    const int t = threadIdx.x;

    // Stage weights (transposed, bf16, swizzled). Global reads coalesced over k.
    for (int i = t; i < 128 * 128; i += 256) {
        int c = i >> 7, k = i & 127;
        int cs = c ^ ((k & 31) << 1);
        sW[k][cs] = __float2bfloat16(Wl[i]);        // Wl[c][k]
        sW[k + 128][cs] = __float2bfloat16(Wr[i]);  // Wr[c][k]
    }

    const int r0 = blockIdx.x * 16;
    // Stage A tile: 16 rows x 256 k. Coalesced global reads, strided LDS writes.
    for (int i = t; i < 16 * 256; i += 256) {
        int r = i >> 8, k = i & 255;
        int rr = r0 + r;
        float v = 0.f;
        if (rr < N) {
            v = (k < 128) ? agg[(size_t)rr * D + k] * invd[rr]
                          : selfx[(size_t)rr * D + (k - 128)];
        }
        sA[k][r] = v;
    }
    __syncthreads();

    const int c = t & 127;
    const int rg = t >> 7;  // 0/1 -> rows rg*8 .. rg*8+7
    float acc[8];
    const float bc = bias[c];
#pragma unroll
    for (int i = 0; i < 8; ++i) acc[i] = bc;

#pragma unroll 4
    for (int k = 0; k < 256; ++k) {
        float w = __bfloat162float(sW[k][c ^ ((k & 31) << 1)]);
        const float4* row = reinterpret_cast<const float4*>(&sA[k][0]);
        float4 a0 = row[rg * 2];
        float4 a1 = row[rg * 2 + 1];
        acc[0] += a0.x * w; acc[1] += a0.y * w; acc[2] += a0.z * w; acc[3] += a0.w * w;
        acc[4] += a1.x * w; acc[5] += a1.y * w; acc[6] += a1.z * w; acc[7] += a1.w * w;
    }

    const int rbase = r0 + rg * 8;
#pragma unroll
    for (int i = 0; i < 8; ++i) {
        int rr = rbase + i;
        if (rr < N) out[(size_t)rr * D + c] = acc[i];
    }
}

extern "C" void kernel_launch(void* const* d_in, const int* in_sizes, int n_in,
                              void* d_out, int out_size, void* d_ws, size_t ws_size,
                              hipStream_t stream) {
    const float* x   = (const float*)d_in[0];
    const void*  ei  = d_in[1];
    const float* Wl1 = (const float*)d_in[2];
    const float* Wr1 = (const float*)d_in[3];
    const float* b1  = (const float*)d_in[4];
    const float* Wl2 = (const float*)d_in[5];
    const float* Wr2 = (const float*)d_in[6];
    const float* b2  = (const float*)d_in[7];
    float* out = (float*)d_out;

    const int N = in_sizes[0] / D;
    const int E = in_sizes[1] / 2;

    float* h1   = (float*)d_ws;                  // N*D f32
    float* invd = h1 + (size_t)N * D;            // N f32
    int*   deg  = (int*)(invd + N);              // N i32

    const int gemm_grid = (N + 15) / 16;

    // ---- layer 1: agg1 lives in d_out ----
    hipMemsetAsync(deg, 0, (size_t)N * sizeof(int), stream);
    hipMemsetAsync(out, 0, (size_t)N * D * sizeof(float), stream);
    deg_count_kernel<<<(E + 255) / 256, 256, 0, stream>>>(ei, E, deg);
    scatter_add_kernel<<<8192, 256, 0, stream>>>(x, ei, E, out);
    inv_deg_kernel<<<(N + 255) / 256, 256, 0, stream>>>(deg, invd, N);
    sage_gemm_kernel<<<gemm_grid, 256, 0, stream>>>(out, invd, x, Wl1, Wr1, b1, h1, N);

    // ---- layer 2: agg2 in d_out, GEMM in-place into d_out ----
    hipMemsetAsync(out, 0, (size_t)N * D * sizeof(float), stream);
    scatter_add_kernel<<<8192, 256, 0, stream>>>(h1, ei, E, out);
    sage_gemm_kernel<<<gemm_grid, 256, 0, stream>>>(out, invd, h1, Wl2, Wr2, b2, out, N);
}

// Round 2
// 1095.365 us; speedup vs baseline: 3.0624x; 3.0624x over previous
//
#include <hip/hip_runtime.h>
#include <hip/hip_bf16.h>

#define D 128
#define SCAN_CHUNK 1024

// ---------- edge-index dtype detection (int64 vs int32, on-device) ----------
__device__ __forceinline__ bool ei_is64(const int* ei32) {
    // For int64 data with values in [0, 2^31), every high word is 0.
    return (ei32[1] | ei32[3] | ei32[5] | ei32[7]) == 0;
}

__device__ __forceinline__ int get_idx(const void* ei, bool is64, long long pos) {
    return is64 ? (int)((const long long*)ei)[pos] : ((const int*)ei)[pos];
}

// ---------- degree histogram into rs ----------
__global__ __launch_bounds__(256) void deg_count_kernel(const void* __restrict__ ei,
                                                        int E, int* __restrict__ rs) {
    bool is64 = ei_is64((const int*)ei);
    int i = blockIdx.x * blockDim.x + threadIdx.x;
    if (i < E) {
        int d = get_idx(ei, is64, (long long)E + i);
        atomicAdd(&rs[d], 1);
    }
}

// ---------- 3-kernel exclusive scan over rs[0..N) ----------
__global__ __launch_bounds__(256) void scan_partial_kernel(int* __restrict__ rs, int N,
                                                           int* __restrict__ bsum) {
    __shared__ int s[SCAN_CHUNK];
    int base = blockIdx.x * SCAN_CHUNK;
    for (int j = threadIdx.x; j < SCAN_CHUNK; j += 256) {
        int i = base + j;
        s[j] = (i < N) ? rs[i] : 0;
    }
    __syncthreads();
    if (threadIdx.x == 0) {
        int run = 0;
        for (int j = 0; j < SCAN_CHUNK; ++j) { int t = s[j]; s[j] = run; run += t; }
        bsum[blockIdx.x] = run;
    }
    __syncthreads();
    for (int j = threadIdx.x; j < SCAN_CHUNK; j += 256) {
        int i = base + j;
        if (i < N) rs[i] = s[j];
    }
}

__global__ void scan_top_kernel(int* __restrict__ bsum, int nb) {
    if (threadIdx.x == 0 && blockIdx.x == 0) {
        int run = 0;
        for (int j = 0; j < nb; ++j) { int t = bsum[j]; bsum[j] = run; run += t; }
    }
}

__global__ __launch_bounds__(256) void scan_add_kernel(int* __restrict__ rs, int N,
                                                       const int* __restrict__ bsum) {
    int i = blockIdx.x * blockDim.x + threadIdx.x;
    if (i < N) rs[i] += bsum[i >> 10];  // SCAN_CHUNK = 1024
}

// ---------- CSR fill: after this, rs[v] = end offset of v ----------
__global__ __launch_bounds__(256) void fill_csr_kernel(const void* __restrict__ ei, int E,
                                                       int* __restrict__ rs,
                                                       int* __restrict__ col) {
    bool is64 = ei_is64((const int*)ei);
    int i = blockIdx.x * blockDim.x + threadIdx.x;
    if (i < E) {
        int s = get_idx(ei, is64, i);
        int d = get_idx(ei, is64, (long long)E + i);
        int pos = atomicAdd(&rs[d], 1);
        col[pos] = s;
    }
}

// ---------- gather-aggregate (mean): one wave per node, lane = 2 floats ----------
__global__ __launch_bounds__(256) void aggregate_mean_kernel(
    const float* __restrict__ x, const int* __restrict__ rs,
    const int* __restrict__ col, float* __restrict__ outm, int N) {
    int lane = threadIdx.x & 63;
    int v = blockIdx.x * 4 + (threadIdx.x >> 6);
    if (v >= N) return;
    int start = (v == 0) ? 0 : rs[v - 1];
    int end = rs[v];
    float2 acc = {0.f, 0.f};
    int e = start;
    for (; e + 2 <= end; e += 2) {
        int s0 = col[e], s1 = col[e + 1];
        const float2 v0 = *reinterpret_cast<const float2*>(x + (size_t)s0 * D + lane * 2);
        const float2 v1 = *reinterpret_cast<const float2*>(x + (size_t)s1 * D + lane * 2);
        acc.x += v0.x + v1.x;
        acc.y += v0.y + v1.y;
    }
    if (e < end) {
        int s0 = col[e];
        const float2 v0 = *reinterpret_cast<const float2*>(x + (size_t)s0 * D + lane * 2);
        acc.x += v0.x;
        acc.y += v0.y;
    }
    float inv = (end > start) ? 1.0f / (float)(end - start) : 0.f;
    float2 r = {acc.x * inv, acc.y * inv};
    *reinterpret_cast<float2*>(outm + (size_t)v * D + lane * 2) = r;
}

// ---------- fused SAGE GEMM: out[r][c] = b[c] + sum_k A[r][k]*W[k][c]
//   A = concat(mean[r], selfx[r])  (K=256), W = concat(Wl^T, Wr^T)
//   In-place safe when out == mean (block stages its own rows before writing).
__global__ __launch_bounds__(256) void sage_gemm_kernel(
    const float* __restrict__ mean, const float* __restrict__ selfx,
    const float* __restrict__ Wl, const float* __restrict__ Wr,
    const float* __restrict__ bias, float* __restrict__ out, int N) {
    __shared__ __hip_bfloat16 sW[256][128];  // 64 KB
    __shared__ float sA[256][16];            // 16 KB
    const int t = threadIdx.x;

    for (int i = t; i < 128 * 128; i += 256) {
        int c = i >> 7, k = i & 127;
        int cs = c ^ ((k & 31) << 1);
        sW[k][cs] = __float2bfloat16(Wl[i]);        // Wl[c][k]
        sW[k + 128][cs] = __float2bfloat16(Wr[i]);  // Wr[c][k]
    }

    const int r0 = blockIdx.x * 16;
    for (int i = t; i < 16 * 256; i += 256) {
        int r = i >> 8, k = i & 255;
        int rr = r0 + r;
        float v = 0.f;
        if (rr < N) {
            v = (k < 128) ? mean[(size_t)rr * D + k]
                          : selfx[(size_t)rr * D + (k - 128)];
        }
        sA[k][r] = v;
    }
    __syncthreads();

    const int c = t & 127;
    const int rg = t >> 7;
    float acc[8];
    const float bc = bias[c];
#pragma unroll
    for (int i = 0; i < 8; ++i) acc[i] = bc;

#pragma unroll 4
    for (int k = 0; k < 256; ++k) {
        float w = __bfloat162float(sW[k][c ^ ((k & 31) << 1)]);
        const float4* row = reinterpret_cast<const float4*>(&sA[k][0]);
        float4 a0 = row[rg * 2];
        float4 a1 = row[rg * 2 + 1];
        acc[0] += a0.x * w; acc[1] += a0.y * w; acc[2] += a0.z * w; acc[3] += a0.w * w;
        acc[4] += a1.x * w; acc[5] += a1.y * w; acc[6] += a1.z * w; acc[7] += a1.w * w;
    }

    const int rbase = r0 + rg * 8;
#pragma unroll
    for (int i = 0; i < 8; ++i) {
        int rr = rbase + i;
        if (rr < N) out[(size_t)rr * D + c] = acc[i];
    }
}

extern "C" void kernel_launch(void* const* d_in, const int* in_sizes, int n_in,
                              void* d_out, int out_size, void* d_ws, size_t ws_size,
                              hipStream_t stream) {
    const float* x   = (const float*)d_in[0];
    const void*  ei  = d_in[1];
    const float* Wl1 = (const float*)d_in[2];
    const float* Wr1 = (const float*)d_in[3];
    const float* b1  = (const float*)d_in[4];
    const float* Wl2 = (const float*)d_in[5];
    const float* Wr2 = (const float*)d_in[6];
    const float* b2  = (const float*)d_in[7];
    float* out = (float*)d_out;

    const int N = in_sizes[0] / D;
    const int E = in_sizes[1] / 2;
    const int nb = (N + SCAN_CHUNK - 1) / SCAN_CHUNK;

    float* h1   = (float*)d_ws;                  // N*D f32
    int*   rs   = (int*)(h1 + (size_t)N * D);    // N i32
    int*   col  = rs + N;                        // E i32
    int*   bsum = col + E;                       // nb i32

    const int egrid = (E + 255) / 256;
    const int gemm_grid = (N + 15) / 16;
    const int agg_grid = (N + 3) / 4;

    // ---- build CSR (once, shared by both layers) ----
    hipMemsetAsync(rs, 0, (size_t)N * sizeof(int), stream);
    deg_count_kernel<<<egrid, 256, 0, stream>>>(ei, E, rs);
    scan_partial_kernel<<<nb, 256, 0, stream>>>(rs, N, bsum);
    scan_top_kernel<<<1, 64, 0, stream>>>(bsum, nb);
    scan_add_kernel<<<(N + 255) / 256, 256, 0, stream>>>(rs, N, bsum);
    fill_csr_kernel<<<egrid, 256, 0, stream>>>(ei, E, rs, col);

    // ---- layer 1: mean in d_out, GEMM -> h1 ----
    aggregate_mean_kernel<<<agg_grid, 256, 0, stream>>>(x, rs, col, out, N);
    sage_gemm_kernel<<<gemm_grid, 256, 0, stream>>>(out, x, Wl1, Wr1, b1, h1, N);

    // ---- layer 2: mean in d_out, GEMM in-place -> d_out ----
    aggregate_mean_kernel<<<agg_grid, 256, 0, stream>>>(h1, rs, col, out, N);
    sage_gemm_kernel<<<gemm_grid, 256, 0, stream>>>(out, h1, Wl2, Wr2, b2, out, N);
}

// Round 3
// 460.851 us; speedup vs baseline: 7.2787x; 2.3768x over previous
//
#include <hip/hip_runtime.h>
#include <hip/hip_bf16.h>

#define D 128
#define SCAN_CHUNK 1024

typedef __attribute__((ext_vector_type(8))) short bf16x8;
typedef __attribute__((ext_vector_type(4))) float f32x4;

__device__ __forceinline__ float bf_lo(unsigned u) {
    union { unsigned u; float f; } c; c.u = u << 16; return c.f;
}
__device__ __forceinline__ float bf_hi(unsigned u) {
    union { unsigned u; float f; } c; c.u = u & 0xffff0000u; return c.f;
}

// ---------- edge-index dtype detection (int64 vs int32, on-device) ----------
__device__ __forceinline__ bool ei_is64(const int* ei32) {
    return (ei32[1] | ei32[3] | ei32[5] | ei32[7]) == 0;
}
__device__ __forceinline__ int get_idx(const void* ei, bool is64, long long pos) {
    return is64 ? (int)((const long long*)ei)[pos] : ((const int*)ei)[pos];
}

// ---------- f32 -> bf16 bulk convert ----------
__global__ __launch_bounds__(256) void cvt_bf16_kernel(const float* __restrict__ in,
                                                       __hip_bfloat16* __restrict__ outb,
                                                       long long n) {
    long long i = ((long long)blockIdx.x * 256 + threadIdx.x) * 4;
    if (i + 3 < n) {
        float4 v = *reinterpret_cast<const float4*>(in + i);
        __hip_bfloat16 o[4];
        o[0] = __float2bfloat16(v.x); o[1] = __float2bfloat16(v.y);
        o[2] = __float2bfloat16(v.z); o[3] = __float2bfloat16(v.w);
        *reinterpret_cast<ushort4*>(outb + i) = *reinterpret_cast<ushort4*>(o);
    } else {
        for (; i < n; ++i) outb[i] = __float2bfloat16(in[i]);
    }
}

// ---------- build Wcat[n][256] = [Wl[n][0..127] | Wr[n][0..127]] in bf16 ----------
__global__ __launch_bounds__(256) void cvt_w_kernel(const float* __restrict__ Wl,
                                                    const float* __restrict__ Wr,
                                                    __hip_bfloat16* __restrict__ Wcat) {
    int i = blockIdx.x * 256 + threadIdx.x;  // 16384 threads
    int c = i >> 7, k = i & 127;
    Wcat[c * 256 + k] = __float2bfloat16(Wl[i]);
    Wcat[c * 256 + 128 + k] = __float2bfloat16(Wr[i]);
}

// ---------- degree histogram ----------
__global__ __launch_bounds__(256) void deg_count_kernel(const void* __restrict__ ei,
                                                        int E, int* __restrict__ rs) {
    bool is64 = ei_is64((const int*)ei);
    int i = blockIdx.x * blockDim.x + threadIdx.x;
    if (i < E) {
        int d = get_idx(ei, is64, (long long)E + i);
        atomicAdd(&rs[d], 1);
    }
}

// ---------- 3-kernel exclusive scan ----------
__global__ __launch_bounds__(256) void scan_partial_kernel(int* __restrict__ rs, int N,
                                                           int* __restrict__ bsum) {
    __shared__ int s[SCAN_CHUNK];
    int base = blockIdx.x * SCAN_CHUNK;
    for (int j = threadIdx.x; j < SCAN_CHUNK; j += 256) {
        int i = base + j;
        s[j] = (i < N) ? rs[i] : 0;
    }
    __syncthreads();
    if (threadIdx.x == 0) {
        int run = 0;
        for (int j = 0; j < SCAN_CHUNK; ++j) { int t = s[j]; s[j] = run; run += t; }
        bsum[blockIdx.x] = run;
    }
    __syncthreads();
    for (int j = threadIdx.x; j < SCAN_CHUNK; j += 256) {
        int i = base + j;
        if (i < N) rs[i] = s[j];
    }
}

__global__ void scan_top_kernel(int* __restrict__ bsum, int nb) {
    if (threadIdx.x == 0 && blockIdx.x == 0) {
        int run = 0;
        for (int j = 0; j < nb; ++j) { int t = bsum[j]; bsum[j] = run; run += t; }
    }
}

__global__ __launch_bounds__(256) void scan_add_kernel(int* __restrict__ rs, int N,
                                                       const int* __restrict__ bsum) {
    int i = blockIdx.x * blockDim.x + threadIdx.x;
    if (i < N) rs[i] += bsum[i >> 10];
}

// ---------- CSR fill: after this, rs[v] = end offset of v ----------
__global__ __launch_bounds__(256) void fill_csr_kernel(const void* __restrict__ ei, int E,
                                                       int* __restrict__ rs,
                                                       int* __restrict__ col) {
    bool is64 = ei_is64((const int*)ei);
    int i = blockIdx.x * blockDim.x + threadIdx.x;
    if (i < E) {
        int s = get_idx(ei, is64, i);
        int d = get_idx(ei, is64, (long long)E + i);
        int pos = atomicAdd(&rs[d], 1);
        col[pos] = s;
    }
}

// ---------- gather-aggregate (mean), bf16 in / bf16 out ----------
// One wave per node; quarter-wave (16 lanes x 16B) covers one 256B row, so one
// dwordx4 instruction gathers 4 edges. f32 accumulate, cross-quarter shfl reduce.
__global__ __launch_bounds__(256) void aggregate_mean_kernel(
    const ushort* __restrict__ xb, const int* __restrict__ rs,
    const int* __restrict__ col, ushort* __restrict__ outm, int N) {
    int t = threadIdx.x;
    int v = blockIdx.x * 4 + (t >> 6);
    if (v >= N) return;
    int lane = t & 63, q = lane >> 4, lc = lane & 15;
    int start = v ? rs[v - 1] : 0, end = rs[v];
    float a[8] = {0.f, 0.f, 0.f, 0.f, 0.f, 0.f, 0.f, 0.f};
    for (int e = start + q; e < end; e += 4) {
        int s = col[e];
        uint4 d = *reinterpret_cast<const uint4*>(xb + (size_t)s * D + lc * 8);
        a[0] += bf_lo(d.x); a[1] += bf_hi(d.x);
        a[2] += bf_lo(d.y); a[3] += bf_hi(d.y);
        a[4] += bf_lo(d.z); a[5] += bf_hi(d.z);
        a[6] += bf_lo(d.w); a[7] += bf_hi(d.w);
    }
#pragma unroll
    for (int i = 0; i < 8; ++i) {
        a[i] += __shfl_xor(a[i], 16);
        a[i] += __shfl_xor(a[i], 32);
    }
    if (q == 0) {
        float inv = (end > start) ? 1.0f / (float)(end - start) : 0.f;
        __hip_bfloat16 o[8];
#pragma unroll
        for (int i = 0; i < 8; ++i) o[i] = __float2bfloat16(a[i] * inv);
        *reinterpret_cast<uint4*>(outm + (size_t)v * D + lc * 8) =
            *reinterpret_cast<uint4*>(o);
    }
}

// ---------- MFMA GEMM: out[m][n] = bias[n] + sum_k A[m][k] * Wcat[n][k]
//   A = [meanb | selfb] (K=256, bf16), no LDS: A/B frags are contiguous 16B loads.
//   Wave: 2 m-tiles (32 rows) x 8 n-tiles (128 cols). Block: 4 waves = 128 rows.
template <typename OutT>
__global__ __launch_bounds__(256) void sage_mfma_kernel(
    const ushort* __restrict__ Ab, const ushort* __restrict__ Sb,
    const ushort* __restrict__ Wc, const float* __restrict__ bias,
    OutT* __restrict__ out, int N) {
    const int t = threadIdx.x;
    const int lane = t & 63, w = t >> 6;
    const int lm = lane & 15;
    const int ksub = (lane >> 4) * 8;
    const int mbase = blockIdx.x * 128 + w * 32;

    int r0 = mbase + lm;      if (r0 >= N) r0 = N - 1;
    int r1 = mbase + 16 + lm; if (r1 >= N) r1 = N - 1;

    f32x4 acc[2][8];
#pragma unroll
    for (int j = 0; j < 8; ++j) {
        float bv = bias[j * 16 + lm];
        acc[0][j] = {bv, bv, bv, bv};
        acc[1][j] = {bv, bv, bv, bv};
    }

    const ushort* A0 = Ab + (size_t)r0 * D + ksub;
    const ushort* A1 = Ab + (size_t)r1 * D + ksub;
    const ushort* S0 = Sb + (size_t)r0 * D + ksub;
    const ushort* S1 = Sb + (size_t)r1 * D + ksub;
    const ushort* Wp = Wc + (size_t)lm * 256 + ksub;

#pragma unroll
    for (int s = 0; s < 8; ++s) {
        bf16x8 a0, a1;
        if (s < 4) {
            a0 = *reinterpret_cast<const bf16x8*>(A0 + s * 32);
            a1 = *reinterpret_cast<const bf16x8*>(A1 + s * 32);
        } else {
            a0 = *reinterpret_cast<const bf16x8*>(S0 + (s - 4) * 32);
            a1 = *reinterpret_cast<const bf16x8*>(S1 + (s - 4) * 32);
        }
#pragma unroll
        for (int j = 0; j < 8; ++j) {
            bf16x8 b = *reinterpret_cast<const bf16x8*>(Wp + (size_t)j * 16 * 256 + s * 32);
            acc[0][j] = __builtin_amdgcn_mfma_f32_16x16x32_bf16(a0, b, acc[0][j], 0, 0, 0);
            acc[1][j] = __builtin_amdgcn_mfma_f32_16x16x32_bf16(a1, b, acc[1][j], 0, 0, 0);
        }
    }

    const int rr = (lane >> 4) * 4;
#pragma unroll
    for (int mt = 0; mt < 2; ++mt) {
#pragma unroll
        for (int r = 0; r < 4; ++r) {
            int row = mbase + mt * 16 + rr + r;
            if (row < N) {
#pragma unroll
                for (int j = 0; j < 8; ++j) {
                    float val = acc[mt][j][r];
                    if constexpr (sizeof(OutT) == 2)
                        out[(size_t)row * D + j * 16 + lm] = __float2bfloat16(val);
                    else
                        out[(size_t)row * D + j * 16 + lm] = val;
                }
            }
        }
    }
}

extern "C" void kernel_launch(void* const* d_in, const int* in_sizes, int n_in,
                              void* d_out, int out_size, void* d_ws, size_t ws_size,
                              hipStream_t stream) {
    const float* x   = (const float*)d_in[0];
    const void*  ei  = d_in[1];
    const float* Wl1 = (const float*)d_in[2];
    const float* Wr1 = (const float*)d_in[3];
    const float* b1  = (const float*)d_in[4];
    const float* Wl2 = (const float*)d_in[5];
    const float* Wr2 = (const float*)d_in[6];
    const float* b2  = (const float*)d_in[7];
    float* out = (float*)d_out;

    const int N = in_sizes[0] / D;
    const int E = in_sizes[1] / 2;
    const int nb = (N + SCAN_CHUNK - 1) / SCAN_CHUNK;
    const long long ND = (long long)N * D;

    // ws layout (bf16 = ushort)
    ushort* meanb = (ushort*)d_ws;                      // N*D
    ushort* h1b   = meanb + ND;                         // N*D
    ushort* Wc1   = h1b + ND;                           // 128*256
    ushort* Wc2   = Wc1 + 128 * 256;                    // 128*256
    int*    rs    = (int*)(Wc2 + 128 * 256);            // N
    int*    col   = rs + N;                             // E
    int*    bsum  = col + E;                            // nb
    // xb lives in d_out's first half (dead before GEMM2 overwrites d_out)
    ushort* xb = (ushort*)d_out;

    const int egrid = (E + 255) / 256;

    // ---- converts ----
    cvt_bf16_kernel<<<(int)((ND / 4 + 255) / 256), 256, 0, stream>>>(
        x, (__hip_bfloat16*)xb, ND);
    cvt_w_kernel<<<64, 256, 0, stream>>>(Wl1, Wr1, (__hip_bfloat16*)Wc1);
    cvt_w_kernel<<<64, 256, 0, stream>>>(Wl2, Wr2, (__hip_bfloat16*)Wc2);

    // ---- build CSR (shared by both layers) ----
    hipMemsetAsync(rs, 0, (size_t)N * sizeof(int), stream);
    deg_count_kernel<<<egrid, 256, 0, stream>>>(ei, E, rs);
    scan_partial_kernel<<<nb, 256, 0, stream>>>(rs, N, bsum);
    scan_top_kernel<<<1, 64, 0, stream>>>(bsum, nb);
    scan_add_kernel<<<(N + 255) / 256, 256, 0, stream>>>(rs, N, bsum);
    fill_csr_kernel<<<egrid, 256, 0, stream>>>(ei, E, rs, col);

    const int agg_grid = (N + 3) / 4;
    const int gemm_grid = (N + 127) / 128;

    // ---- layer 1 ----
    aggregate_mean_kernel<<<agg_grid, 256, 0, stream>>>(xb, rs, col, meanb, N);
    sage_mfma_kernel<__hip_bfloat16><<<gemm_grid, 256, 0, stream>>>(
        meanb, xb, Wc1, b1, (__hip_bfloat16*)h1b, N);

    // ---- layer 2 ----
    aggregate_mean_kernel<<<agg_grid, 256, 0, stream>>>(h1b, rs, col, meanb, N);
    sage_mfma_kernel<float><<<gemm_grid, 256, 0, stream>>>(
        meanb, h1b, Wc2, b2, out, N);
}

// Round 4
// 302.445 us; speedup vs baseline: 11.0910x; 1.5238x over previous
//
#include <hip/hip_runtime.h>
#include <hip/hip_bf16.h>

#define D 128
#define SCAN_CHUNK 1024
#define TE 2048  // edges per partition block

typedef __attribute__((ext_vector_type(8))) short bf16x8;
typedef __attribute__((ext_vector_type(4))) float f32x4;

__device__ __forceinline__ float bf_lo(unsigned u) {
    union { unsigned u; float f; } c; c.u = u << 16; return c.f;
}
__device__ __forceinline__ float bf_hi(unsigned u) {
    union { unsigned u; float f; } c; c.u = u & 0xffff0000u; return c.f;
}

// ---------- edge-index dtype detection (int64 vs int32, on-device) ----------
__device__ __forceinline__ bool ei_is64(const int* ei32) {
    return (ei32[1] | ei32[3] | ei32[5] | ei32[7]) == 0;
}
__device__ __forceinline__ int get_idx(const void* ei, bool is64, long long pos) {
    return is64 ? (int)((const long long*)ei)[pos] : ((const int*)ei)[pos];
}

// ---------- f32 -> bf16 bulk convert ----------
__global__ __launch_bounds__(256) void cvt_bf16_kernel(const float* __restrict__ in,
                                                       __hip_bfloat16* __restrict__ outb,
                                                       long long n) {
    long long i = ((long long)blockIdx.x * 256 + threadIdx.x) * 4;
    if (i + 3 < n) {
        float4 v = *reinterpret_cast<const float4*>(in + i);
        __hip_bfloat16 o[4];
        o[0] = __float2bfloat16(v.x); o[1] = __float2bfloat16(v.y);
        o[2] = __float2bfloat16(v.z); o[3] = __float2bfloat16(v.w);
        *reinterpret_cast<ushort4*>(outb + i) = *reinterpret_cast<ushort4*>(o);
    } else {
        for (; i < n; ++i) outb[i] = __float2bfloat16(in[i]);
    }
}

// ---------- build Wcat[n][256] = [Wl[n][0..127] | Wr[n][0..127]] in bf16 ----------
__global__ __launch_bounds__(256) void cvt_w_kernel(const float* __restrict__ Wl,
                                                    const float* __restrict__ Wr,
                                                    __hip_bfloat16* __restrict__ Wcat) {
    int i = blockIdx.x * 256 + threadIdx.x;  // 16384 threads
    int c = i >> 7, k = i & 127;
    Wcat[c * 256 + k] = __float2bfloat16(Wl[i]);
    Wcat[c * 256 + 128 + k] = __float2bfloat16(Wr[i]);
}

// ---------- partition pass 1: per-block LDS histogram over buckets ----------
__global__ __launch_bounds__(256) void part_hist_kernel(const void* __restrict__ ei, int E,
                                                        int NB, int NBLK, int SH,
                                                        int* __restrict__ histT) {
    __shared__ int h[512];
    const int t = threadIdx.x;
    for (int b = t; b < 512; b += 256) h[b] = 0;
    bool is64 = ei_is64((const int*)ei);
    __syncthreads();
    const int base = blockIdx.x * TE;
    for (int i = t; i < TE; i += 256) {
        int e = base + i;
        if (e < E) {
            int d = get_idx(ei, is64, (long long)E + e);
            atomicAdd(&h[d >> SH], 1);
        }
    }
    __syncthreads();
    for (int b = t; b < NB; b += 256) histT[b * NBLK + blockIdx.x] = h[b];
}

// ---------- 3-kernel exclusive scan over arr[0..Ntot) ----------
__global__ __launch_bounds__(256) void scan_partial_kernel(int* __restrict__ arr, int Ntot,
                                                           int* __restrict__ bsum) {
    __shared__ int s[SCAN_CHUNK];
    int base = blockIdx.x * SCAN_CHUNK;
    for (int j = threadIdx.x; j < SCAN_CHUNK; j += 256) {
        int i = base + j;
        s[j] = (i < Ntot) ? arr[i] : 0;
    }
    __syncthreads();
    if (threadIdx.x == 0) {
        int run = 0;
        for (int j = 0; j < SCAN_CHUNK; ++j) { int t = s[j]; s[j] = run; run += t; }
        bsum[blockIdx.x] = run;
    }
    __syncthreads();
    for (int j = threadIdx.x; j < SCAN_CHUNK; j += 256) {
        int i = base + j;
        if (i < Ntot) arr[i] = s[j];
    }
}

__global__ __launch_bounds__(256) void scan_top_kernel(int* __restrict__ bsum, int nb) {
    __shared__ int s[1024];
    const int t = threadIdx.x;
    for (int j = t; j < nb; j += 256) s[j] = bsum[j];
    __syncthreads();
    if (t == 0) {
        int run = 0;
        for (int j = 0; j < nb; ++j) { int v = s[j]; s[j] = run; run += v; }
    }
    __syncthreads();
    for (int j = t; j < nb; j += 256) bsum[j] = s[j];
}

__global__ __launch_bounds__(256) void scan_add_kernel(int* __restrict__ arr, int Ntot,
                                                       const int* __restrict__ bsum) {
    int i = blockIdx.x * blockDim.x + threadIdx.x;
    if (i < Ntot) arr[i] += bsum[i >> 10];
}

// ---------- partition pass 2: scatter edges grouped by bucket (LDS cursors) ----------
__global__ __launch_bounds__(256) void part_scatter_kernel(const void* __restrict__ ei, int E,
                                                           int NB, int NBLK, int SH,
                                                           const int* __restrict__ histT,
                                                           uint2* __restrict__ ebuf) {
    __shared__ int cur[512];
    const int t = threadIdx.x;
    bool is64 = ei_is64((const int*)ei);
    for (int b = t; b < NB; b += 256) cur[b] = histT[b * NBLK + blockIdx.x];
    __syncthreads();
    const int base = blockIdx.x * TE;
    for (int i = t; i < TE; i += 256) {
        int e = base + i;
        if (e < E) {
            int s = get_idx(ei, is64, e);
            int d = get_idx(ei, is64, (long long)E + e);
            int pos = atomicAdd(&cur[d >> SH], 1);
            ebuf[pos] = make_uint2((unsigned)s, (unsigned)d);
        }
    }
}

// ---------- per-bucket CSR: LDS node-histogram + scan, contiguous col writes ----------
__global__ __launch_bounds__(256) void bucket_csr_kernel(const uint2* __restrict__ ebuf,
                                                         const int* __restrict__ histT,
                                                         int NB, int NBLK, int SH, int E,
                                                         int N, int* __restrict__ rs,
                                                         int* __restrict__ col) {
    const int b = blockIdx.x, t = threadIdx.x;
    const int nodes = 1 << SH;  // 256
    __shared__ int h[256];
    __shared__ int cur[256];
    __shared__ int sse[2];
    if (t == 0) {
        sse[0] = histT[b * NBLK];
        sse[1] = (b + 1 < NB) ? histT[(b + 1) * NBLK] : E;
    }
    for (int l = t; l < nodes; l += 256) h[l] = 0;
    __syncthreads();
    const int bstart = sse[0], bend = sse[1];
    const int node0 = b << SH;
    for (int i = bstart + t; i < bend; i += 256) {
        int d = (int)ebuf[i].y;
        atomicAdd(&h[d - node0], 1);
    }
    __syncthreads();
    // inclusive Hillis-Steele scan over h[0..nodes)
    for (int off = 1; off < nodes; off <<= 1) {
        int v = 0;
        if (t < nodes && t >= off) v = h[t - off];
        __syncthreads();
        if (t < nodes && t >= off) h[t] += v;
        __syncthreads();
    }
    if (t < nodes) {
        int node = node0 + t;
        if (node < N) rs[node] = bstart + h[t];      // end offset
        cur[t] = bstart + (t ? h[t - 1] : 0);        // start offset
    }
    __syncthreads();
    for (int i = bstart + t; i < bend; i += 256) {
        uint2 ed = ebuf[i];
        int pos = atomicAdd(&cur[(int)ed.y - node0], 1);
        col[pos] = (int)ed.x;
    }
}

// ---------- gather-aggregate (mean), bf16 in / bf16 out ----------
__global__ __launch_bounds__(256) void aggregate_mean_kernel(
    const ushort* __restrict__ xb, const int* __restrict__ rs,
    const int* __restrict__ col, ushort* __restrict__ outm, int N) {
    int t = threadIdx.x;
    int v = blockIdx.x * 4 + (t >> 6);
    if (v >= N) return;
    int lane = t & 63, q = lane >> 4, lc = lane & 15;
    int start = v ? rs[v - 1] : 0, end = rs[v];
    float a[8] = {0.f, 0.f, 0.f, 0.f, 0.f, 0.f, 0.f, 0.f};
    for (int e = start + q; e < end; e += 4) {
        int s = col[e];
        uint4 d = *reinterpret_cast<const uint4*>(xb + (size_t)s * D + lc * 8);
        a[0] += bf_lo(d.x); a[1] += bf_hi(d.x);
        a[2] += bf_lo(d.y); a[3] += bf_hi(d.y);
        a[4] += bf_lo(d.z); a[5] += bf_hi(d.z);
        a[6] += bf_lo(d.w); a[7] += bf_hi(d.w);
    }
#pragma unroll
    for (int i = 0; i < 8; ++i) {
        a[i] += __shfl_xor(a[i], 16);
        a[i] += __shfl_xor(a[i], 32);
    }
    if (q == 0) {
        float inv = (end > start) ? 1.0f / (float)(end - start) : 0.f;
        __hip_bfloat16 o[8];
#pragma unroll
        for (int i = 0; i < 8; ++i) o[i] = __float2bfloat16(a[i] * inv);
        *reinterpret_cast<uint4*>(outm + (size_t)v * D + lc * 8) =
            *reinterpret_cast<uint4*>(o);
    }
}

// ---------- MFMA GEMM: out[m][n] = bias[n] + sum_k A[m][k] * Wcat[n][k] ----------
template <typename OutT>
__global__ __launch_bounds__(256) void sage_mfma_kernel(
    const ushort* __restrict__ Ab, const ushort* __restrict__ Sb,
    const ushort* __restrict__ Wc, const float* __restrict__ bias,
    OutT* __restrict__ out, int N) {
    const int t = threadIdx.x;
    const int lane = t & 63, w = t >> 6;
    const int lm = lane & 15;
    const int ksub = (lane >> 4) * 8;
    const int mbase = blockIdx.x * 128 + w * 32;

    int r0 = mbase + lm;      if (r0 >= N) r0 = N - 1;
    int r1 = mbase + 16 + lm; if (r1 >= N) r1 = N - 1;

    f32x4 acc[2][8];
#pragma unroll
    for (int j = 0; j < 8; ++j) {
        float bv = bias[j * 16 + lm];
        acc[0][j] = {bv, bv, bv, bv};
        acc[1][j] = {bv, bv, bv, bv};
    }

    const ushort* A0 = Ab + (size_t)r0 * D + ksub;
    const ushort* A1 = Ab + (size_t)r1 * D + ksub;
    const ushort* S0 = Sb + (size_t)r0 * D + ksub;
    const ushort* S1 = Sb + (size_t)r1 * D + ksub;
    const ushort* Wp = Wc + (size_t)lm * 256 + ksub;

#pragma unroll
    for (int s = 0; s < 8; ++s) {
        bf16x8 a0, a1;
        if (s < 4) {
            a0 = *reinterpret_cast<const bf16x8*>(A0 + s * 32);
            a1 = *reinterpret_cast<const bf16x8*>(A1 + s * 32);
        } else {
            a0 = *reinterpret_cast<const bf16x8*>(S0 + (s - 4) * 32);
            a1 = *reinterpret_cast<const bf16x8*>(S1 + (s - 4) * 32);
        }
#pragma unroll
        for (int j = 0; j < 8; ++j) {
            bf16x8 b = *reinterpret_cast<const bf16x8*>(Wp + (size_t)j * 16 * 256 + s * 32);
            acc[0][j] = __builtin_amdgcn_mfma_f32_16x16x32_bf16(a0, b, acc[0][j], 0, 0, 0);
            acc[1][j] = __builtin_amdgcn_mfma_f32_16x16x32_bf16(a1, b, acc[1][j], 0, 0, 0);
        }
    }

    const int rr = (lane >> 4) * 4;
#pragma unroll
    for (int mt = 0; mt < 2; ++mt) {
#pragma unroll
        for (int r = 0; r < 4; ++r) {
            int row = mbase + mt * 16 + rr + r;
            if (row < N) {
#pragma unroll
                for (int j = 0; j < 8; ++j) {
                    float val = acc[mt][j][r];
                    if constexpr (sizeof(OutT) == 2)
                        out[(size_t)row * D + j * 16 + lm] = __float2bfloat16(val);
                    else
                        out[(size_t)row * D + j * 16 + lm] = val;
                }
            }
        }
    }
}

extern "C" void kernel_launch(void* const* d_in, const int* in_sizes, int n_in,
                              void* d_out, int out_size, void* d_ws, size_t ws_size,
                              hipStream_t stream) {
    const float* x   = (const float*)d_in[0];
    const void*  ei  = d_in[1];
    const float* Wl1 = (const float*)d_in[2];
    const float* Wr1 = (const float*)d_in[3];
    const float* b1  = (const float*)d_in[4];
    const float* Wl2 = (const float*)d_in[5];
    const float* Wr2 = (const float*)d_in[6];
    const float* b2  = (const float*)d_in[7];
    float* out = (float*)d_out;

    const int N = in_sizes[0] / D;
    const int E = in_sizes[1] / 2;
    const long long ND = (long long)N * D;

    // bucket shift: keep NB <= 512 (N=100000 -> SH=8, NB=391)
    int SH = 8;
    while (((N + (1 << SH) - 1) >> SH) > 512) ++SH;
    const int NB = (N + (1 << SH) - 1) >> SH;
    const int NBLK = (E + TE - 1) / TE;
    const int Ntot = NB * NBLK;
    const int nb2 = (Ntot + SCAN_CHUNK - 1) / SCAN_CHUNK;  // must be <= 1024

    // ws layout (bf16 = ushort)
    ushort* meanb = (ushort*)d_ws;                      // N*D
    ushort* h1b   = meanb + ND;                         // N*D
    ushort* Wc1   = h1b + ND;                           // 128*256
    ushort* Wc2   = Wc1 + 128 * 256;                    // 128*256
    int*    rs    = (int*)(Wc2 + 128 * 256);            // N
    int*    col   = rs + N;                             // E
    // transient aliases (dead before their hosts are written):
    int*    histT = (int*)meanb;                        // NB*NBLK (meanb written later)
    int*    bsum  = histT + Ntot;                       // nb2
    uint2*  ebuf  = (uint2*)h1b;                        // E pairs (h1b written later)
    // xb lives in d_out's first half (dead before GEMM2 overwrites d_out)
    ushort* xb = (ushort*)d_out;

    // ---- converts ----
    cvt_bf16_kernel<<<(int)((ND / 4 + 255) / 256), 256, 0, stream>>>(
        x, (__hip_bfloat16*)xb, ND);
    cvt_w_kernel<<<64, 256, 0, stream>>>(Wl1, Wr1, (__hip_bfloat16*)Wc1);
    cvt_w_kernel<<<64, 256, 0, stream>>>(Wl2, Wr2, (__hip_bfloat16*)Wc2);

    // ---- build CSR via two-level counting sort (LDS atomics only) ----
    part_hist_kernel<<<NBLK, 256, 0, stream>>>(ei, E, NB, NBLK, SH, histT);
    scan_partial_kernel<<<nb2, 256, 0, stream>>>(histT, Ntot, bsum);
    scan_top_kernel<<<1, 256, 0, stream>>>(bsum, nb2);
    scan_add_kernel<<<(Ntot + 255) / 256, 256, 0, stream>>>(histT, Ntot, bsum);
    part_scatter_kernel<<<NBLK, 256, 0, stream>>>(ei, E, NB, NBLK, SH, histT, ebuf);
    bucket_csr_kernel<<<NB, 256, 0, stream>>>(ebuf, histT, NB, NBLK, SH, E, N, rs, col);

    const int agg_grid = (N + 3) / 4;
    const int gemm_grid = (N + 127) / 128;

    // ---- layer 1 ----
    aggregate_mean_kernel<<<agg_grid, 256, 0, stream>>>(xb, rs, col, meanb, N);
    sage_mfma_kernel<__hip_bfloat16><<<gemm_grid, 256, 0, stream>>>(
        meanb, xb, Wc1, b1, (__hip_bfloat16*)h1b, N);

    // ---- layer 2 ----
    aggregate_mean_kernel<<<agg_grid, 256, 0, stream>>>(h1b, rs, col, meanb, N);
    sage_mfma_kernel<float><<<gemm_grid, 256, 0, stream>>>(
        meanb, h1b, Wc2, b2, out, N);
}